// Round 3
// baseline (530.370 us; speedup 1.0000x reference)
//
#include <hip/hip_runtime.h>
#include <hip/hip_bf16.h>

// Problem constants
#define Mdim 2048
#define Ndim 8192
#define Kdim 8192
#define BM 128
#define BN 128
#define BK 64

typedef __bf16 bf16x8 __attribute__((ext_vector_type(8)));
typedef float f32x16 __attribute__((ext_vector_type(16)));
typedef unsigned short ushort8 __attribute__((ext_vector_type(8)));

__device__ __forceinline__ unsigned short f2bf_rne(float f) {
    unsigned u = __float_as_uint(f);
    u += 0x7fffu + ((u >> 16) & 1u);
    return (unsigned short)(u >> 16);
}

// ---------------------------------------------------------------------------
// Kernel 1 (fused prep): blocks [0,8192) dequantize packed 3-bit -> bf16 W;
// blocks [8192,10240) convert x fp32 -> bf16.
// Dequant: block handles 1024 groups (8192 weights); packed bytes staged via
// LDS with coalesced int4 loads; decode = 3-level cndmask tree per weight.
// ---------------------------------------------------------------------------
#define DQG 1024
__global__ __launch_bounds__(256) void k_prep(const int* __restrict__ packed,
                                              const float* __restrict__ cb,
                                              const float* __restrict__ x,
                                              unsigned short* __restrict__ W,
                                              unsigned short* __restrict__ xb) {
    __shared__ int sp[3 * DQG];                       // 12 KB
    const int t = threadIdx.x;
    if (blockIdx.x < 8192) {
        const size_t gbase = (size_t)blockIdx.x * DQG;
        const int4* pv = (const int4*)(packed + gbase * 3);   // 768 int4/block
        int4* sv = (int4*)sp;
        sv[t]       = pv[t];
        sv[t + 256] = pv[t + 256];
        sv[t + 512] = pv[t + 512];
        __syncthreads();
#pragma unroll
        for (int c = 0; c < 4; ++c) {
            const int g = t + 256 * c;                // local group 0..1023
            int p0 = sp[3 * g + 0];
            int p1 = sp[3 * g + 1];
            int p2 = sp[3 * g + 2];
            unsigned bits = (unsigned)(p0 & 255) | ((unsigned)(p1 & 255) << 8) |
                            ((unsigned)(p2 & 255) << 16);
            const size_t gg = gbase + g;
            const float4* cv = (const float4*)(cb + ((gg >> 4) << 3));
            float4 c0 = cv[0];
            float4 c1 = cv[1];
            ushort8 o;
#pragma unroll
            for (int i = 0; i < 8; ++i) {
                unsigned id = (bits >> (3 * i)) & 7u;
                float a0 = (id & 1) ? c0.y : c0.x;
                float a1 = (id & 1) ? c0.w : c0.z;
                float a2 = (id & 1) ? c1.y : c1.x;
                float a3 = (id & 1) ? c1.w : c1.z;
                float b0 = (id & 2) ? a1 : a0;
                float b1 = (id & 2) ? a3 : a2;
                float v  = (id & 4) ? b1 : b0;
                o[i] = f2bf_rne(v);
            }
            *(ushort8*)(W + (gg << 3)) = o;           // 16B coalesced store
        }
    } else {
        size_t tt = (size_t)(blockIdx.x - 8192) * 256 + t;   // 0 .. 524287
        const float4* xv = (const float4*)x;
#pragma unroll
        for (int c = 0; c < 4; ++c) {
            size_t u = tt + (size_t)524288 * c;
            float4 a = xv[2 * u + 0];
            float4 b = xv[2 * u + 1];
            ushort8 o;
            o[0] = f2bf_rne(a.x); o[1] = f2bf_rne(a.y);
            o[2] = f2bf_rne(a.z); o[3] = f2bf_rne(a.w);
            o[4] = f2bf_rne(b.x); o[5] = f2bf_rne(b.y);
            o[6] = f2bf_rne(b.z); o[7] = f2bf_rne(b.w);
            ((ushort8*)xb)[u] = o;
        }
    }
}

// ---------------------------------------------------------------------------
// Kernel 2: bf16 GEMM  C[M,N] = A[M,K] * B[N,K]^T  (both K-major)
// 128x128 tile, BK=64, 4 waves (2x2), each wave 64x64 via 2x2 grid of
// mfma_f32_32x32x16_bf16 (2495 TF ubench vs 2176 for 16x16x32 — m119).
// LDS XOR-swizzle at 16B-chunk granularity: row r's k-chunk c at slot
// c ^ f(r), f(r) = (r ^ (r>>3)) & 7 — spreads rows r,r+8,r+16,r+24 that
// share (lane&7) in the 32x32 fragment-read pattern across distinct slots.
// global_load_lds dest stays base+lane*16 (required); swizzle encoded in
// per-lane GLOBAL source column.
// ---------------------------------------------------------------------------
__device__ __forceinline__ void gld16(const unsigned short* g, unsigned short* l) {
    __builtin_amdgcn_global_load_lds(
        (const __attribute__((address_space(1))) unsigned int*)g,
        (__attribute__((address_space(3))) unsigned int*)l, 16, 0, 0);
}

__device__ __forceinline__ int fsw(int r) { return (r ^ (r >> 3)) & 7; }

__global__ __launch_bounds__(256) void k_gemm(const unsigned short* __restrict__ A,
                                              const unsigned short* __restrict__ B,
                                              float* __restrict__ C) {
    __shared__ unsigned short As[BM * BK];   // 16 KB
    __shared__ unsigned short Bs[BN * BK];   // 16 KB

    const int tid  = threadIdx.x;
    const int lane = tid & 63;
    const int wave = tid >> 6;
    const int waveM = wave >> 1;             // 0..1
    const int waveN = wave & 1;              // 0..1
    const int bm = blockIdx.y * BM;
    const int bn = blockIdx.x * BN;

    // Staging: call j covers tile rows [j*32, j*32+32). Thread t fills LDS
    // physical chunk j*256+t == (row = j*32 + t/8, slot = t&7); that slot
    // holds k-chunk (t&7) ^ f(row) -> encode in the global source column.
    const int srow = tid >> 3;               // 0..31
    const unsigned short* srcA[4];
    const unsigned short* srcB[4];
#pragma unroll
    for (int j = 0; j < 4; ++j) {
        int row = j * 32 + srow;
        int scol = ((tid & 7) ^ fsw(row)) * 8;
        srcA[j] = A + (size_t)(bm + row) * Kdim + scol;
        srcB[j] = B + (size_t)(bn + row) * Kdim + scol;
    }
    unsigned short* alp = &As[tid * 8];
    unsigned short* blp = &Bs[tid * 8];

    f32x16 acc[2][2];
#pragma unroll
    for (int i = 0; i < 2; ++i)
#pragma unroll
        for (int j = 0; j < 2; ++j)
#pragma unroll
            for (int r = 0; r < 16; ++r) acc[i][j][r] = 0.f;

    const int r31 = lane & 31;
    const int hi  = lane >> 5;               // 0..1 (k-half)
    // fragment row for tile i: rA = waveM*64 + i*32 + r31; precompute
    // hA[i] = hi ^ f(rA); LDS slot for k-step ks = (ks<<1) ^ hA[i].
    int hA[2], hB[2], rowA[2], rowB[2];
#pragma unroll
    for (int i = 0; i < 2; ++i) {
        rowA[i] = waveM * 64 + i * 32 + r31;
        rowB[i] = waveN * 64 + i * 32 + r31;
        hA[i] = hi ^ fsw(rowA[i]);
        hB[i] = hi ^ fsw(rowB[i]);
    }

    for (int kt = 0; kt < Kdim; kt += BK) {
#pragma unroll
        for (int j = 0; j < 4; ++j) {
            gld16(srcA[j] + kt, alp + j * 2048);
            gld16(srcB[j] + kt, blp + j * 2048);
        }
        __syncthreads();

#pragma unroll
        for (int ks = 0; ks < 4; ++ks) {
            bf16x8 af[2], bfr[2];
#pragma unroll
            for (int i = 0; i < 2; ++i)
                af[i] = *(const bf16x8*)(&As[rowA[i] * BK + (((ks << 1) ^ hA[i]) * 8)]);
#pragma unroll
            for (int j = 0; j < 2; ++j)
                bfr[j] = *(const bf16x8*)(&Bs[rowB[j] * BK + (((ks << 1) ^ hB[j]) * 8)]);
#pragma unroll
            for (int i = 0; i < 2; ++i)
#pragma unroll
                for (int j = 0; j < 2; ++j)
                    acc[i][j] = __builtin_amdgcn_mfma_f32_32x32x16_bf16(
                        af[i], bfr[j], acc[i][j], 0, 0, 0);
        }
        __syncthreads();
    }

    // Epilogue: C/D layout col = lane&31, row = (reg&3) + 8*(reg>>2) + 4*hi
    // (m74/m101, HW-verified)
#pragma unroll
    for (int i = 0; i < 2; ++i) {
#pragma unroll
        for (int j = 0; j < 2; ++j) {
            int colg = bn + waveN * 64 + j * 32 + r31;
            int rowg = bm + waveM * 64 + i * 32 + 4 * hi;
#pragma unroll
            for (int r = 0; r < 16; ++r) {
                int row = rowg + (r & 3) + 8 * (r >> 2);
                C[(size_t)row * Ndim + colg] = acc[i][j][r];
            }
        }
    }
}

// ---------------------------------------------------------------------------
extern "C" void kernel_launch(void* const* d_in, const int* in_sizes, int n_in,
                              void* d_out, int out_size, void* d_ws, size_t ws_size,
                              hipStream_t stream) {
    const float* x      = (const float*)d_in[0];   // 2048 x 8192 fp32
    const int*   packed = (const int*)d_in[1];     // 25165824 int32 (one byte each)
    const float* cb     = (const float*)d_in[2];   // 524288 x 8 fp32
    float* out = (float*)d_out;                    // 2048 x 8192 fp32

    unsigned short* Wb = (unsigned short*)d_ws;                          // 128 MB bf16 W
    unsigned short* Xb = (unsigned short*)d_ws + (size_t)Ndim * Kdim;    // 32 MB bf16 x

    // 1) fused dequant (blocks 0..8191) + x convert (blocks 8192..10239)
    k_prep<<<10240, 256, 0, stream>>>(packed, cb, x, Wb, Xb);
    // 2) GEMM
    dim3 grid(Ndim / BN, Mdim / BM);   // (64, 16)
    k_gemm<<<grid, 256, 0, stream>>>(Xb, Wb, out);
}

// Round 4
// 519.103 us; speedup vs baseline: 1.0217x; 1.0217x over previous
//
#include <hip/hip_runtime.h>
#include <hip/hip_bf16.h>

// Problem constants
#define Mdim 2048
#define Ndim 8192
#define Kdim 8192
#define BM 128
#define BN 128
#define BK 64

typedef __bf16 bf16x8 __attribute__((ext_vector_type(8)));
typedef float f32x4 __attribute__((ext_vector_type(4)));
typedef unsigned short ushort8 __attribute__((ext_vector_type(8)));
typedef unsigned short ushort4v __attribute__((ext_vector_type(4)));

__device__ __forceinline__ unsigned short f2bf_rne(float f) {
    unsigned u = __float_as_uint(f);
    u += 0x7fffu + ((u >> 16) & 1u);
    return (unsigned short)(u >> 16);
}

__device__ __forceinline__ ushort8 decode8(unsigned bits, float4 c0, float4 c1) {
    ushort8 o;
#pragma unroll
    for (int i = 0; i < 8; ++i) {
        unsigned id = (bits >> (3 * i)) & 7u;
        float a0 = (id & 1) ? c0.y : c0.x;
        float a1 = (id & 1) ? c0.w : c0.z;
        float a2 = (id & 1) ? c1.y : c1.x;
        float a3 = (id & 1) ? c1.w : c1.z;
        float b0 = (id & 2) ? a1 : a0;
        float b1 = (id & 2) ? a3 : a2;
        float v  = (id & 4) ? b1 : b0;
        o[i] = f2bf_rne(v);
    }
    return o;
}

// ---------------------------------------------------------------------------
// Fused prep, LDS-free, max TLP (r1-style dequant was faster than r2's LDS
// staging — latency chains, not bandwidth, dominated).
// Blocks [0,16384): dequant, 2 groups/thread via 3 aligned int2 loads
//   (the 3 loads per wave touch the same 24 cachelines -> L1 absorbs).
// Blocks [16384,32768): x fp32->bf16, one float4 -> ushort4 per thread,
//   lane-contiguous (perfect coalescing per instruction).
// ---------------------------------------------------------------------------
__global__ __launch_bounds__(256) void k_prep(const int* __restrict__ packed,
                                              const float* __restrict__ cb,
                                              const float* __restrict__ x,
                                              unsigned short* __restrict__ W,
                                              unsigned short* __restrict__ xb) {
    const int t = threadIdx.x;
    if (blockIdx.x < 16384) {
        const size_t th = (size_t)blockIdx.x * 256 + t;    // 0..4194303
        const size_t g0 = th * 2;                          // even group
        const int2* pv = (const int2*)(packed + g0 * 3);   // 6 ints, 8B aligned
        int2 q0 = pv[0], q1 = pv[1], q2 = pv[2];
        unsigned bits0 = (unsigned)(q0.x & 255) | ((unsigned)(q0.y & 255) << 8) |
                         ((unsigned)(q1.x & 255) << 16);
        unsigned bits1 = (unsigned)(q1.y & 255) | ((unsigned)(q2.x & 255) << 8) |
                         ((unsigned)(q2.y & 255) << 16);
        const float4* cv0 = (const float4*)(cb + ((g0 >> 4) << 3));
        const float4* cv1 = (const float4*)(cb + (((g0 + 1) >> 4) << 3));
        float4 c00 = cv0[0], c01 = cv0[1];
        float4 c10 = cv1[0], c11 = cv1[1];
        ushort8 o0 = decode8(bits0, c00, c01);
        ushort8 o1 = decode8(bits1, c10, c11);
        unsigned short* wp = W + (g0 << 3);                // 32B contiguous
        *(ushort8*)(wp)     = o0;
        *(ushort8*)(wp + 8) = o1;
    } else {
        const size_t u = (size_t)(blockIdx.x - 16384) * 256 + t;  // 0..4194303
        float4 a = ((const float4*)x)[u];
        ushort4v o;
        o[0] = f2bf_rne(a.x); o[1] = f2bf_rne(a.y);
        o[2] = f2bf_rne(a.z); o[3] = f2bf_rne(a.w);
        ((ushort4v*)xb)[u] = o;
    }
}

// ---------------------------------------------------------------------------
// bf16 GEMM  C[M,N] = A[M,K] * B[N,K]^T  (both K-major) — round-2 version:
// 128x128 tile, BK=64, 4 waves (2x2), each 64x64 via 4x4 mfma 16x16x32.
// (32x32x16 variant measured SLOWER (329 vs 315 us) despite higher ubench
// rate — this structure is staging-latency-bound, not issue-bound.)
// LDS XOR-swizzle at 16B-chunk granularity: row r's k-chunk kc at slot
// kc ^ (r&7); global_load_lds dest stays base+lane*16 (required), swizzle
// encoded in per-lane GLOBAL source column. Bank conflicts measured 0.
// ---------------------------------------------------------------------------
__device__ __forceinline__ void gld16(const unsigned short* g, unsigned short* l) {
    __builtin_amdgcn_global_load_lds(
        (const __attribute__((address_space(1))) unsigned int*)g,
        (__attribute__((address_space(3))) unsigned int*)l, 16, 0, 0);
}

__global__ __launch_bounds__(256) void k_gemm(const unsigned short* __restrict__ A,
                                              const unsigned short* __restrict__ B,
                                              float* __restrict__ C) {
    __shared__ unsigned short As[BM * BK];   // 16 KB
    __shared__ unsigned short Bs[BN * BK];   // 16 KB

    const int tid  = threadIdx.x;
    const int lane = tid & 63;
    const int wave = tid >> 6;
    const int waveM = wave >> 1;             // 0..1
    const int waveN = wave & 1;              // 0..1
    const int bm = blockIdx.y * BM;
    const int bn = blockIdx.x * BN;

    const int srow = tid >> 3;                               // 0..31
    const int scol = (((tid & 7) ^ ((tid >> 3) & 7))) * 8;   // swizzled k-chunk
    const unsigned short* agp = A + (size_t)(bm + srow) * Kdim + scol;
    const unsigned short* bgp = B + (size_t)(bn + srow) * Kdim + scol;
    unsigned short* alp = &As[tid * 8];
    unsigned short* blp = &Bs[tid * 8];

    f32x4 acc[4][4];
    const f32x4 zero = {0.f, 0.f, 0.f, 0.f};
#pragma unroll
    for (int i = 0; i < 4; ++i)
#pragma unroll
        for (int j = 0; j < 4; ++j) acc[i][j] = zero;

    const int r15 = lane & 15;
    const int q   = lane >> 4;               // 0..3
    const int rlo = r15 & 7;                 // row&7 for all fragment rows

    for (int kt = 0; kt < Kdim; kt += BK) {
#pragma unroll
        for (int j = 0; j < 4; ++j) {
            gld16(agp + (size_t)(j * 32) * Kdim + kt, alp + j * 2048);
            gld16(bgp + (size_t)(j * 32) * Kdim + kt, blp + j * 2048);
        }
        __syncthreads();

#pragma unroll
        for (int kk = 0; kk < 2; ++kk) {
            const int slot = ((kk * 4 + q) ^ rlo) * 8;   // swizzled LDS slot
            bf16x8 af[4], bfr[4];
#pragma unroll
            for (int i = 0; i < 4; ++i)
                af[i] = *(const bf16x8*)(&As[(waveM * 64 + i * 16 + r15) * BK + slot]);
#pragma unroll
            for (int j = 0; j < 4; ++j)
                bfr[j] = *(const bf16x8*)(&Bs[(waveN * 64 + j * 16 + r15) * BK + slot]);
#pragma unroll
            for (int i = 0; i < 4; ++i)
#pragma unroll
                for (int j = 0; j < 4; ++j)
                    acc[i][j] = __builtin_amdgcn_mfma_f32_16x16x32_bf16(
                        af[i], bfr[j], acc[i][j], 0, 0, 0);
        }
        __syncthreads();
    }

    // Epilogue: C/D layout col = lane&15, row = (lane>>4)*4 + r  (m89/m91)
#pragma unroll
    for (int i = 0; i < 4; ++i) {
#pragma unroll
        for (int j = 0; j < 4; ++j) {
            int row = bm + waveM * 64 + i * 16 + q * 4;
            int col = bn + waveN * 64 + j * 16 + r15;
            float* outp = C + (size_t)row * Ndim + col;
#pragma unroll
            for (int r = 0; r < 4; ++r)
                outp[(size_t)r * Ndim] = acc[i][j][r];
        }
    }
}

// ---------------------------------------------------------------------------
extern "C" void kernel_launch(void* const* d_in, const int* in_sizes, int n_in,
                              void* d_out, int out_size, void* d_ws, size_t ws_size,
                              hipStream_t stream) {
    const float* x      = (const float*)d_in[0];   // 2048 x 8192 fp32
    const int*   packed = (const int*)d_in[1];     // 25165824 int32 (one byte each)
    const float* cb     = (const float*)d_in[2];   // 524288 x 8 fp32
    float* out = (float*)d_out;                    // 2048 x 8192 fp32

    unsigned short* Wb = (unsigned short*)d_ws;                          // 128 MB bf16 W
    unsigned short* Xb = (unsigned short*)d_ws + (size_t)Ndim * Kdim;    // 32 MB bf16 x

    // 1) fused prep: dequant (blocks 0..16383) + x convert (16384..32767)
    k_prep<<<32768, 256, 0, stream>>>(packed, cb, x, Wb, Xb);
    // 2) GEMM
    dim3 grid(Ndim / BN, Mdim / BM);   // (64, 16)
    k_gemm<<<grid, 256, 0, stream>>>(Xb, Wb, out);
}